// Round 1
// baseline (167.122 us; speedup 1.0000x reference)
//
#include <hip/hip_runtime.h>

#define NROWS 2048
#define KDIM  768
#define L     40

// ---------------------------------------------------------------------------
// Kernel 1: hxb = x @ W1[:, :768]^T + b1   (2048 x 40)
//           hy  = y @ W1[:, 768:]^T        (2048 x 40)
// grid (128, 2), block 256. blockIdx.y: 0 -> x (hxb), 1 -> y (hy)
// Each block: 16 rows; 16 threads per row split K=768 into interleaved chunks
// (k = q*64 + seg*4) so wave lanes read contiguous 256B spans of A and W.
// ---------------------------------------------------------------------------
__global__ __launch_bounds__(256) void k_proj(const float* __restrict__ x,
                                              const float* __restrict__ y,
                                              const float* __restrict__ W1,
                                              const float* __restrict__ b1,
                                              float* __restrict__ hxb,
                                              float* __restrict__ hy) {
    const int which = blockIdx.y;
    const float* __restrict__ A = which ? y : x;
    float* __restrict__ out = which ? hy : hxb;
    const int tid = threadIdx.x;
    const int r   = tid >> 4;    // 0..15 row within block
    const int seg = tid & 15;    // 0..15 K-segment
    const int row0 = blockIdx.x * 16;
    const int row  = row0 + r;

    // partials: [16 rows][40 outs][17 segs(pad)]
    __shared__ float sh[16 * 680];

    // load this thread's 48 A elements (k = q*64 + seg*4, q=0..11)
    float4 a[12];
    const float* arow = A + (size_t)row * KDIM;
#pragma unroll
    for (int q = 0; q < 12; ++q)
        a[q] = *(const float4*)(arow + q * 64 + seg * 4);

    const float* wbase = W1 + which * KDIM;
    for (int o = 0; o < L; ++o) {
        const float* wrow = wbase + (size_t)o * (2 * KDIM);
        float s = 0.f;
#pragma unroll
        for (int q = 0; q < 12; ++q) {
            float4 w = *(const float4*)(wrow + q * 64 + seg * 4);
            s += a[q].x * w.x + a[q].y * w.y + a[q].z * w.z + a[q].w * w.w;
        }
        sh[r * 680 + o * 17 + seg] = s;
    }
    __syncthreads();

    // reduce 16 segments -> 640 outputs; consecutive lanes -> consecutive o
    for (int idx = tid; idx < 16 * L; idx += 256) {
        int rr = idx / L;
        int o  = idx - rr * L;
        float s = 0.f;
        int base = rr * 680 + o * 17;
#pragma unroll
        for (int q = 0; q < 16; ++q) s += sh[base + q];
        if (!which) s += b1[o];                       // fold b1 into hxb
        out[(size_t)(row0 + rr) * L + o] = s;
    }
}

// ---------------------------------------------------------------------------
// Kernel 2: pairwise sum of exp(T_ij - 1) + diagonal T0 sum.
//   acc_ij = sum_k relu(hy[i,k] + hxb[j,k]) * W2[k]       (b1 already in hxb)
//   sumExp += exp(acc_ij + b2 - 1);  if (i==j) sumT0 += acc_ij + b2
// Tile: BI=128 (i) x BJ=64 (j), block 256 = 16(ty,i) x 16(tx,j),
// micro-tile 8x4 with lane-interleaved rows: i = i0+ty+16u, j = j0+tx+16v.
// LDS row stride 44 floats -> ay reads conflict-free, ax reads 2-way (free).
// ---------------------------------------------------------------------------
#define BI 128
#define BJ 64
#define STRD 44

__global__ __launch_bounds__(256) void k_pair(const float* __restrict__ hxb,
                                              const float* __restrict__ hy,
                                              const float* __restrict__ W2,
                                              const float* __restrict__ b2p,
                                              float* __restrict__ sums) {
    __shared__ float shy[BI * STRD];
    __shared__ float shx[BJ * STRD];
    __shared__ float sw2[STRD];
    __shared__ float red[8];

    const int tid = threadIdx.x;
    const int i0 = blockIdx.x * BI;
    const int j0 = blockIdx.y * BJ;

    // stage hy tile (128 x 40), contiguous float4 walk => fully coalesced
    for (int idx = tid; idx < BI * 10; idx += 256) {
        int rr = idx / 10, c = idx - rr * 10;
        float4 v = ((const float4*)(hy + (size_t)i0 * L))[idx];
        *(float4*)(shy + rr * STRD + c * 4) = v;
    }
    for (int idx = tid; idx < BJ * 10; idx += 256) {
        int rr = idx / 10, c = idx - rr * 10;
        float4 v = ((const float4*)(hxb + (size_t)j0 * L))[idx];
        *(float4*)(shx + rr * STRD + c * 4) = v;
    }
    if (tid < 10) ((float4*)sw2)[tid] = ((const float4*)W2)[tid];
    __syncthreads();

    const int tx = tid & 15, ty = tid >> 4;

    float acc[8][4];
#pragma unroll
    for (int u = 0; u < 8; ++u)
#pragma unroll
        for (int v = 0; v < 4; ++v) acc[u][v] = 0.f;

#pragma unroll
    for (int k4 = 0; k4 < 10; ++k4) {
        float4 w = *(const float4*)(sw2 + k4 * 4);
        float4 ay[8], ax[4];
#pragma unroll
        for (int u = 0; u < 8; ++u)
            ay[u] = *(const float4*)(shy + (ty + 16 * u) * STRD + k4 * 4);
#pragma unroll
        for (int v = 0; v < 4; ++v)
            ax[v] = *(const float4*)(shx + (tx + 16 * v) * STRD + k4 * 4);
#pragma unroll
        for (int u = 0; u < 8; ++u)
#pragma unroll
            for (int v = 0; v < 4; ++v) {
                float t;
                t = ay[u].x + ax[v].x; t = fmaxf(t, 0.f); acc[u][v] += t * w.x;
                t = ay[u].y + ax[v].y; t = fmaxf(t, 0.f); acc[u][v] += t * w.y;
                t = ay[u].z + ax[v].z; t = fmaxf(t, 0.f); acc[u][v] += t * w.z;
                t = ay[u].w + ax[v].w; t = fmaxf(t, 0.f); acc[u][v] += t * w.w;
            }
    }

    const float b2v = b2p[0];
    float sumE = 0.f, sumT = 0.f;
#pragma unroll
    for (int u = 0; u < 8; ++u)
#pragma unroll
        for (int v = 0; v < 4; ++v) {
            int gi = i0 + ty + 16 * u;
            int gj = j0 + tx + 16 * v;
            float val = acc[u][v] + b2v;
            if (gi == gj) sumT += val;
            sumE += __expf(val - 1.f);
        }

    // wave (64-lane) reduction, then cross-wave via LDS, one atomic per block
#pragma unroll
    for (int off = 32; off > 0; off >>= 1) {
        sumE += __shfl_down(sumE, off);
        sumT += __shfl_down(sumT, off);
    }
    int wid = tid >> 6;
    if ((tid & 63) == 0) { red[wid] = sumE; red[4 + wid] = sumT; }
    __syncthreads();
    if (tid == 0) {
        float e = red[0] + red[1] + red[2] + red[3];
        float t = red[4] + red[5] + red[6] + red[7];
        atomicAdd(&sums[1], e);
        atomicAdd(&sums[0], t);
    }
}

// ---------------------------------------------------------------------------
// Kernel 3: lower_bound = sumT0/N - sumExp/N^2
// ---------------------------------------------------------------------------
__global__ void k_fin(const float* __restrict__ sums, float* __restrict__ out) {
    const float invN = 1.0f / (float)NROWS;
    out[0] = sums[0] * invN - sums[1] * invN * invN;
}

extern "C" void kernel_launch(void* const* d_in, const int* in_sizes, int n_in,
                              void* d_out, int out_size, void* d_ws, size_t ws_size,
                              hipStream_t stream) {
    const float* x  = (const float*)d_in[0];
    const float* y  = (const float*)d_in[1];
    const float* W1 = (const float*)d_in[2];
    const float* b1 = (const float*)d_in[3];
    const float* W2 = (const float*)d_in[4];
    const float* b2 = (const float*)d_in[5];
    float* out = (float*)d_out;

    float* wsf  = (float*)d_ws;
    float* sums = wsf;                 // [0]=sumT0, [1]=sumExp
    float* hxb  = wsf + 16;            // 2048*40, b1 folded in
    float* hy   = hxb + NROWS * L;     // 2048*40

    hipMemsetAsync(sums, 0, 2 * sizeof(float), stream);
    k_proj<<<dim3(NROWS / 16, 2), 256, 0, stream>>>(x, y, W1, b1, hxb, hy);
    k_pair<<<dim3(NROWS / BI, NROWS / BJ), 256, 0, stream>>>(hxb, hy, W2, b2, sums);
    k_fin<<<1, 1, 0, stream>>>(sums, out);
}

// Round 2
// 116.088 us; speedup vs baseline: 1.4396x; 1.4396x over previous
//
#include <hip/hip_runtime.h>

#define NROWS 2048
#define KDIM  768
#define L     40
#define KCH   6          // K-chunks per matrix (768 = 6 * 128)
#define KCSZ  128        // K per chunk
#define HN    (NROWS * L)   // 81920 floats per h matrix

// ---------------------------------------------------------------------------
// Kernel 1: partial projections with K split across blocks.
//   part[(kc*2+which)*HN + row*L + o] = sum_{k in chunk kc} A[row][k]*W1[o][k']
// grid (128 rowblocks, 6 kchunks, 2 matrices), block 256 = 16 rows x 16 segs.
// Per thread: 2 A float4 + 40*2 W float4 (W chunk 20KB -> L1 resident).
// 1536 blocks -> ~3 resident blocks/CU (LDS 44KB) = 12 waves/CU latency hiding.
// ---------------------------------------------------------------------------
__global__ __launch_bounds__(256) void k_proj(const float* __restrict__ x,
                                              const float* __restrict__ y,
                                              const float* __restrict__ W1,
                                              float* __restrict__ part) {
    const int kc    = blockIdx.y;
    const int which = blockIdx.z;
    const float* __restrict__ A = which ? y : x;
    const int tid = threadIdx.x;
    const int r   = tid >> 4;    // 0..15 row within block
    const int seg = tid & 15;    // 0..15 K-segment (8 floats each)
    const int row0 = blockIdx.x * 16;

    // partials: [16 rows][40 o][16 segs], row stride 688 (==16 mod 32 -> 2-way = free)
    __shared__ float sh[16 * 688];

    // this thread's 8 A elements: k = kc*128 + q*64 + seg*4, q=0..1
    const float* arow = A + (size_t)(row0 + r) * KDIM + kc * KCSZ;
    float4 a0 = *(const float4*)(arow + seg * 4);
    float4 a1 = *(const float4*)(arow + 64 + seg * 4);

    const float* wbase = W1 + (size_t)which * KDIM + kc * KCSZ;
#pragma unroll 8
    for (int o = 0; o < L; ++o) {
        const float* wrow = wbase + (size_t)o * (2 * KDIM);
        float4 w0 = *(const float4*)(wrow + seg * 4);
        float4 w1 = *(const float4*)(wrow + 64 + seg * 4);
        float s = a0.x * w0.x + a0.y * w0.y + a0.z * w0.z + a0.w * w0.w
                + a1.x * w1.x + a1.y * w1.y + a1.z * w1.z + a1.w * w1.w;
        sh[r * 688 + o * 17 + seg] = s;
    }
    __syncthreads();

    // reduce 16 segments -> 640 outputs; consecutive lanes -> consecutive o
    float* pout = part + (size_t)(kc * 2 + which) * HN + (size_t)row0 * L;
    for (int idx = tid; idx < 16 * L; idx += 256) {
        int rr = idx / L;
        int o  = idx - rr * L;
        float s = 0.f;
        int base = rr * 688 + o * 17;
#pragma unroll
        for (int q = 0; q < 16; ++q) s += sh[base + q];
        pout[idx] = s;
    }
}

// ---------------------------------------------------------------------------
// Kernel 1b: reduce the 6 K-chunk partials -> hxb (b1 folded in) and hy.
// 163840 threads, fully coalesced.
// ---------------------------------------------------------------------------
__global__ __launch_bounds__(256) void k_red(const float* __restrict__ part,
                                             const float* __restrict__ b1,
                                             float* __restrict__ hxb,
                                             float* __restrict__ hy) {
    int gid = blockIdx.x * 256 + threadIdx.x;   // 0 .. 2*HN-1
    int which = gid / HN;
    int rem   = gid - which * HN;
    float s = 0.f;
#pragma unroll
    for (int kc = 0; kc < KCH; ++kc)
        s += part[(size_t)(kc * 2 + which) * HN + rem];
    if (!which) {
        s += b1[rem % L];
        hxb[rem] = s;
    } else {
        hy[rem] = s;
    }
}

// ---------------------------------------------------------------------------
// Kernel 2: pairwise sum of exp(T_ij - 1) + diagonal T0 sum.
//   acc_ij = sum_k relu(hy[i,k] + hxb[j,k]) * W2[k]       (b1 already in hxb)
//   sumExp += exp(acc_ij + b2 - 1);  if (i==j) sumT0 += acc_ij + b2
// Tile: BI=128 (i) x BJ=64 (j), block 256 = 16(ty,i) x 16(tx,j),
// micro-tile 8x4 with lane-interleaved rows: i = i0+ty+16u, j = j0+tx+16v.
// ---------------------------------------------------------------------------
#define BI 128
#define BJ 64
#define STRD 44

__global__ __launch_bounds__(256) void k_pair(const float* __restrict__ hxb,
                                              const float* __restrict__ hy,
                                              const float* __restrict__ W2,
                                              const float* __restrict__ b2p,
                                              float* __restrict__ sums) {
    __shared__ float shy[BI * STRD];
    __shared__ float shx[BJ * STRD];
    __shared__ float sw2[STRD];
    __shared__ float red[8];

    const int tid = threadIdx.x;
    const int i0 = blockIdx.x * BI;
    const int j0 = blockIdx.y * BJ;

    for (int idx = tid; idx < BI * 10; idx += 256) {
        int rr = idx / 10, c = idx - rr * 10;
        float4 v = ((const float4*)(hy + (size_t)i0 * L))[idx];
        *(float4*)(shy + rr * STRD + c * 4) = v;
    }
    for (int idx = tid; idx < BJ * 10; idx += 256) {
        int rr = idx / 10, c = idx - rr * 10;
        float4 v = ((const float4*)(hxb + (size_t)j0 * L))[idx];
        *(float4*)(shx + rr * STRD + c * 4) = v;
    }
    if (tid < 10) ((float4*)sw2)[tid] = ((const float4*)W2)[tid];
    __syncthreads();

    const int tx = tid & 15, ty = tid >> 4;

    float acc[8][4];
#pragma unroll
    for (int u = 0; u < 8; ++u)
#pragma unroll
        for (int v = 0; v < 4; ++v) acc[u][v] = 0.f;

#pragma unroll
    for (int k4 = 0; k4 < 10; ++k4) {
        float4 w = *(const float4*)(sw2 + k4 * 4);
        float4 ay[8], ax[4];
#pragma unroll
        for (int u = 0; u < 8; ++u)
            ay[u] = *(const float4*)(shy + (ty + 16 * u) * STRD + k4 * 4);
#pragma unroll
        for (int v = 0; v < 4; ++v)
            ax[v] = *(const float4*)(shx + (tx + 16 * v) * STRD + k4 * 4);
#pragma unroll
        for (int u = 0; u < 8; ++u)
#pragma unroll
            for (int v = 0; v < 4; ++v) {
                float t;
                t = ay[u].x + ax[v].x; t = fmaxf(t, 0.f); acc[u][v] += t * w.x;
                t = ay[u].y + ax[v].y; t = fmaxf(t, 0.f); acc[u][v] += t * w.y;
                t = ay[u].z + ax[v].z; t = fmaxf(t, 0.f); acc[u][v] += t * w.z;
                t = ay[u].w + ax[v].w; t = fmaxf(t, 0.f); acc[u][v] += t * w.w;
            }
    }

    const float b2v = b2p[0];
    float sumE = 0.f, sumT = 0.f;
#pragma unroll
    for (int u = 0; u < 8; ++u)
#pragma unroll
        for (int v = 0; v < 4; ++v) {
            int gi = i0 + ty + 16 * u;
            int gj = j0 + tx + 16 * v;
            float val = acc[u][v] + b2v;
            if (gi == gj) sumT += val;
            sumE += __expf(val - 1.f);
        }

#pragma unroll
    for (int off = 32; off > 0; off >>= 1) {
        sumE += __shfl_down(sumE, off);
        sumT += __shfl_down(sumT, off);
    }
    int wid = tid >> 6;
    if ((tid & 63) == 0) { red[wid] = sumE; red[4 + wid] = sumT; }
    __syncthreads();
    if (tid == 0) {
        float e = red[0] + red[1] + red[2] + red[3];
        float t = red[4] + red[5] + red[6] + red[7];
        atomicAdd(&sums[1], e);
        atomicAdd(&sums[0], t);
    }
}

// ---------------------------------------------------------------------------
// Kernel 3: lower_bound = sumT0/N - sumExp/N^2
// ---------------------------------------------------------------------------
__global__ void k_fin(const float* __restrict__ sums, float* __restrict__ out) {
    const float invN = 1.0f / (float)NROWS;
    out[0] = sums[0] * invN - sums[1] * invN * invN;
}

extern "C" void kernel_launch(void* const* d_in, const int* in_sizes, int n_in,
                              void* d_out, int out_size, void* d_ws, size_t ws_size,
                              hipStream_t stream) {
    const float* x  = (const float*)d_in[0];
    const float* y  = (const float*)d_in[1];
    const float* W1 = (const float*)d_in[2];
    const float* b1 = (const float*)d_in[3];
    const float* W2 = (const float*)d_in[4];
    const float* b2 = (const float*)d_in[5];
    float* out = (float*)d_out;

    float* wsf  = (float*)d_ws;
    float* sums = wsf;                   // [0]=sumT0, [1]=sumExp
    float* hxb  = wsf + 16;              // 2048*40, b1 folded in
    float* hy   = hxb + HN;              // 2048*40
    float* part = hy + HN;               // 6*2*2048*40 partials

    hipMemsetAsync(sums, 0, 2 * sizeof(float), stream);
    k_proj<<<dim3(NROWS / 16, KCH, 2), 256, 0, stream>>>(x, y, W1, part);
    k_red<<<(2 * HN) / 256, 256, 0, stream>>>(part, b1, hxb, hy);
    k_pair<<<dim3(NROWS / BI, NROWS / BJ), 256, 0, stream>>>(hxb, hy, W2, b2, sums);
    k_fin<<<1, 1, 0, stream>>>(sums, out);
}